// Round 8
// baseline (67.001 us; speedup 1.0000x reference)
//
#include <hip/hip_runtime.h>

// Fredkin6Layer, algebraically reduced to 9 coefs/gate:
//   a = x[b, (3g+1..3g+3) & 4095],  w = softmax(wgts[g])
//   o0 = (w0+w1)a0 + (w2+w3)a1 + (w4+w5)a2
//   o1 = (w3+w5)a0 + (w1+w4)a1 + (w0+w2)a2
//        + (w0-w1+w2-w3)a0a1 + (w1-w0+w4-w5)a0a2 + (w3-w2+w5-w4)a1a2
//   o2 = (a0+a1+a2) - o0 - o1
// Round-5 structure (no LDS, no barriers, register row-pipeline), with
// full-residency launch bounds: 2048 blocks x 8 blocks/CU = whole grid
// co-resident, gt-pair blocks sharing x rows run concurrently on the
// same XCD (1024 % 8 == 0).

constexpr int DIN  = 4096;
constexpr int NG   = 2048;
constexpr int DOUT = 3 * NG;   // 6144
constexpr int GPB  = 1024;     // gates per block tile
constexpr int GPT  = 4;        // gates per thread
constexpr int RPB  = 4;        // rows per block

__global__ __launch_bounds__(256, 8) void fredkin_kernel(
    const float* __restrict__ x,
    const float* __restrict__ wgts,
    float* __restrict__ out)
{
    const int tid = threadIdx.x;
    const int gt  = blockIdx.x >> 10;        // gate tile in HIGH bits
    const int rb  = blockIdx.x & 1023;       // row tile
    const int g0  = gt * GPB;
    const int base = 3 * g0;                 // 0 or 3072
    const int r0  = rb * RPB;

    // ---- per-thread input window: 4 aligned float4 at cols (base+12t+4k)&4095 ----
    const int jb = 12 * tid;
    const float4* xp0; const float4* xp1; const float4* xp2; const float4* xp3;
    {
        int c0 = (base + jb +  0) & (DIN - 1);
        int c1 = (base + jb +  4) & (DIN - 1);
        int c2 = (base + jb +  8) & (DIN - 1);
        int c3 = (base + jb + 12) & (DIN - 1);
        xp0 = reinterpret_cast<const float4*>(x + c0);
        xp1 = reinterpret_cast<const float4*>(x + c1);
        xp2 = reinterpret_cast<const float4*>(x + c2);
        xp3 = reinterpret_cast<const float4*>(x + c3);
    }
    const size_t rs4 = DIN / 4;               // float4 per x row

    // Issue the first row's loads BEFORE the exp-heavy coef math so the
    // ~200cy softmax chain overlaps the first HBM latency.
    size_t ro = (size_t)r0 * rs4;
    float4 f0 = xp0[ro], f1 = xp1[ro], f2 = xp2[ro], f3 = xp3[ro];

    // ---- per-thread coefficients for its 4 gates (softmax in registers) ----
    float cw[GPT][3], dl[GPT][3], qc[GPT][3];
    {
        const float4* wp =
            reinterpret_cast<const float4*>(wgts + (size_t)(g0 + GPT * tid) * 6);
        float4 h0 = wp[0], h1 = wp[1], h2 = wp[2], h3 = wp[3], h4 = wp[4], h5 = wp[5];
        float w[24] = {h0.x,h0.y,h0.z,h0.w, h1.x,h1.y,h1.z,h1.w,
                       h2.x,h2.y,h2.z,h2.w, h3.x,h3.y,h3.z,h3.w,
                       h4.x,h4.y,h4.z,h4.w, h5.x,h5.y,h5.z,h5.w};
        #pragma unroll
        for (int u = 0; u < GPT; ++u) {
            const float* ww = &w[6 * u];
            float m = fmaxf(fmaxf(fmaxf(ww[0], ww[1]), fmaxf(ww[2], ww[3])),
                            fmaxf(ww[4], ww[5]));
            float e0 = __expf(ww[0] - m), e1 = __expf(ww[1] - m),
                  e2 = __expf(ww[2] - m), e3 = __expf(ww[3] - m),
                  e4 = __expf(ww[4] - m), e5 = __expf(ww[5] - m);
            float inv = 1.0f / (e0 + e1 + e2 + e3 + e4 + e5);
            e0 *= inv; e1 *= inv; e2 *= inv; e3 *= inv; e4 *= inv; e5 *= inv;
            cw[u][0] = e0 + e1; cw[u][1] = e2 + e3; cw[u][2] = e4 + e5;
            dl[u][0] = e3 + e5; dl[u][1] = e1 + e4; dl[u][2] = e0 + e2;
            qc[u][0] = e0 - e1 + e2 - e3;
            qc[u][1] = e1 - e0 + e4 - e5;
            qc[u][2] = e3 - e2 + e5 - e4;
        }
    }

    float* op = out + (size_t)r0 * DOUT + base + jb;

    #pragma unroll
    for (int r = 0; r < RPB; ++r) {
        float4 p0, p1, p2, p3;
        if (r + 1 < RPB) {                     // prefetch next row (stays in
            size_t rn = ro + rs4;              //  flight during this row's compute)
            p0 = xp0[rn]; p1 = xp1[rn]; p2 = xp2[rn]; p3 = xp3[rn];
        }

        float a[GPT][3] = { {f0.y, f0.z, f0.w},
                            {f1.x, f1.y, f1.z},
                            {f1.w, f2.x, f2.y},
                            {f2.z, f2.w, f3.x} };
        float o[12];
        #pragma unroll
        for (int u = 0; u < GPT; ++u) {
            float a0 = a[u][0], a1 = a[u][1], a2 = a[u][2];
            float p01 = a0 * a1, p02 = a0 * a2, p12 = a1 * a2;
            float t0 = cw[u][0] * a0 + cw[u][1] * a1 + cw[u][2] * a2;
            float qq = qc[u][0] * p01 + qc[u][1] * p02 + qc[u][2] * p12;
            float t1 = dl[u][0] * a0 + dl[u][1] * a1 + dl[u][2] * a2 + qq;
            float t2 = (a0 + a1 + a2) - t0 - t1;
            o[3*u + 0] = t0; o[3*u + 1] = t1; o[3*u + 2] = t2;
        }
        float4* op4 = reinterpret_cast<float4*>(op);
        op4[0] = make_float4(o[0], o[1], o[2],  o[3]);
        op4[1] = make_float4(o[4], o[5], o[6],  o[7]);
        op4[2] = make_float4(o[8], o[9], o[10], o[11]);

        if (r + 1 < RPB) {
            f0 = p0; f1 = p1; f2 = p2; f3 = p3;
            ro += rs4;
            op += DOUT;
        }
    }
}

extern "C" void kernel_launch(void* const* d_in, const int* in_sizes, int n_in,
                              void* d_out, int out_size, void* d_ws, size_t ws_size,
                              hipStream_t stream) {
    const float* x    = (const float*)d_in[0];   // (4096, 4096) f32
    const float* wgts = (const float*)d_in[1];   // (2048, 6)   f32
    // d_in[2] = connections — deterministic (3g+1+k) % DIN, not needed.
    float* out = (float*)d_out;                  // (4096, 6144) f32

    const int grid = 2 * (4096 / RPB);           // gt in high bit: 2 x 1024 blocks
    fredkin_kernel<<<grid, 256, 0, stream>>>(x, wgts, out);
}

// Round 9
// 41.860 us; speedup vs baseline: 1.6006x; 1.6006x over previous
//
#include <hip/hip_runtime.h>

// Fredkin6Layer, algebraically reduced to 9 coefs/gate:
//   a = x[b, (3g+1..3g+3) & 4095],  w = softmax(wgts[g])
//   o0 = (w0+w1)a0 + (w2+w3)a1 + (w4+w5)a2
//   o1 = (w3+w5)a0 + (w1+w4)a1 + (w0+w2)a2
//        + (w0-w1+w2-w3)a0a1 + (w1-w0+w4-w5)a0a2 + (w3-w2+w5-w4)a1a2
//   o2 = (a0+a1+a2) - o0 - o1
//
// LOW-CONCURRENCY streaming variant. Measured across R4/R5/R7/R8:
// WRITE inflation ~= 0.5 + 0.2*(blocks/CU) -> run at exactly 2 blocks/CU
// (grid 512), each block streaming 16 rows with a 3-buffer register
// pipeline (2-deep prefetch). BW-bound per-wave iter window (~2.2us)
// >> HBM latency (~0.7us), so 8 waves/CU hide latency fine.

constexpr int DIN  = 4096;
constexpr int NG   = 2048;
constexpr int DOUT = 3 * NG;   // 6144
constexpr int GPB  = 1024;     // gates per block tile
constexpr int GPT  = 4;        // gates per thread
constexpr int NRB  = 256;      // row-tile blocks per gate half
constexpr int RPT  = 4;        // rows per tile
constexpr int TPB  = 4;        // tiles per block (stride NRB)
constexpr int NIT  = TPB * RPT;            // 16 rows per block
constexpr int ROWSTEP = RPT * NRB;         // 1024 rows between tiles

__global__ __launch_bounds__(256, 2) void fredkin_kernel(
    const float* __restrict__ x,
    const float* __restrict__ wgts,
    float* __restrict__ out)
{
    const int tid  = threadIdx.x;
    const int gt   = blockIdx.x >> 8;        // gate half; pair (b, b+256) ->
    const int rb   = blockIdx.x & (NRB - 1); //   same XCD (256 % 8 == 0)
    const int g0   = gt * GPB;
    const int base = 3 * g0;                 // 0 or 3072
    const int row0 = rb * RPT;

    // ---- per-thread input window: 4 aligned float4 at cols (base+12t+4k)&4095 ----
    const int jb = 12 * tid;
    const float4* xp0; const float4* xp1; const float4* xp2; const float4* xp3;
    {
        int c0 = (base + jb +  0) & (DIN - 1);
        int c1 = (base + jb +  4) & (DIN - 1);
        int c2 = (base + jb +  8) & (DIN - 1);
        int c3 = (base + jb + 12) & (DIN - 1);
        xp0 = reinterpret_cast<const float4*>(x + c0);
        xp1 = reinterpret_cast<const float4*>(x + c1);
        xp2 = reinterpret_cast<const float4*>(x + c2);
        xp3 = reinterpret_cast<const float4*>(x + c3);
    }
    const size_t rs4 = DIN / 4;              // float4 per x row

    // row for iteration i: row0 + (i>>2)*ROWSTEP + (i&3)   (compile-time d)
    // 3-buffer register rotation, fully unrolled -> all indices static.
    float4 buf[3][4];

    // issue rows 0 and 1 BEFORE the exp-heavy coef math (overlap HBM latency)
    {
        size_t ro = (size_t)row0 * rs4;
        buf[0][0] = xp0[ro]; buf[0][1] = xp1[ro];
        buf[0][2] = xp2[ro]; buf[0][3] = xp3[ro];
        size_t r1 = ro + rs4;
        buf[1][0] = xp0[r1]; buf[1][1] = xp1[r1];
        buf[1][2] = xp2[r1]; buf[1][3] = xp3[r1];
    }

    // ---- per-thread coefficients for its 4 gates (softmax in registers) ----
    float cw[GPT][3], dl[GPT][3], qc[GPT][3];
    {
        const float4* wp =
            reinterpret_cast<const float4*>(wgts + (size_t)(g0 + GPT * tid) * 6);
        float4 h0 = wp[0], h1 = wp[1], h2 = wp[2], h3 = wp[3], h4 = wp[4], h5 = wp[5];
        float w[24] = {h0.x,h0.y,h0.z,h0.w, h1.x,h1.y,h1.z,h1.w,
                       h2.x,h2.y,h2.z,h2.w, h3.x,h3.y,h3.z,h3.w,
                       h4.x,h4.y,h4.z,h4.w, h5.x,h5.y,h5.z,h5.w};
        #pragma unroll
        for (int u = 0; u < GPT; ++u) {
            const float* ww = &w[6 * u];
            float m = fmaxf(fmaxf(fmaxf(ww[0], ww[1]), fmaxf(ww[2], ww[3])),
                            fmaxf(ww[4], ww[5]));
            float e0 = __expf(ww[0] - m), e1 = __expf(ww[1] - m),
                  e2 = __expf(ww[2] - m), e3 = __expf(ww[3] - m),
                  e4 = __expf(ww[4] - m), e5 = __expf(ww[5] - m);
            float inv = 1.0f / (e0 + e1 + e2 + e3 + e4 + e5);
            e0 *= inv; e1 *= inv; e2 *= inv; e3 *= inv; e4 *= inv; e5 *= inv;
            cw[u][0] = e0 + e1; cw[u][1] = e2 + e3; cw[u][2] = e4 + e5;
            dl[u][0] = e3 + e5; dl[u][1] = e1 + e4; dl[u][2] = e0 + e2;
            qc[u][0] = e0 - e1 + e2 - e3;
            qc[u][1] = e1 - e0 + e4 - e5;
            qc[u][2] = e3 - e2 + e5 - e4;
        }
    }

    float* ob = out + (size_t)row0 * DOUT + base + jb;

    #pragma unroll
    for (int i = 0; i < NIT; ++i) {
        constexpr int dmul = 1;  (void)dmul;
        const int cur = i % 3;
        // prefetch row i+2 into the buffer freed two iters ago
        if (i + 2 < NIT) {
            const int nx = (i + 2) % 3;
            const int dn = ((i + 2) >> 2) * ROWSTEP + ((i + 2) & 3);
            size_t ro = (size_t)(row0 + dn) * rs4;
            buf[nx][0] = xp0[ro]; buf[nx][1] = xp1[ro];
            buf[nx][2] = xp2[ro]; buf[nx][3] = xp3[ro];
        }

        float4 f0 = buf[cur][0], f1 = buf[cur][1],
               f2 = buf[cur][2], f3 = buf[cur][3];

        float a[GPT][3] = { {f0.y, f0.z, f0.w},
                            {f1.x, f1.y, f1.z},
                            {f1.w, f2.x, f2.y},
                            {f2.z, f2.w, f3.x} };
        float o[12];
        #pragma unroll
        for (int u = 0; u < GPT; ++u) {
            float a0 = a[u][0], a1 = a[u][1], a2 = a[u][2];
            float p01 = a0 * a1, p02 = a0 * a2, p12 = a1 * a2;
            float t0 = cw[u][0] * a0 + cw[u][1] * a1 + cw[u][2] * a2;
            float qq = qc[u][0] * p01 + qc[u][1] * p02 + qc[u][2] * p12;
            float t1 = dl[u][0] * a0 + dl[u][1] * a1 + dl[u][2] * a2 + qq;
            float t2 = (a0 + a1 + a2) - t0 - t1;
            o[3*u + 0] = t0; o[3*u + 1] = t1; o[3*u + 2] = t2;
        }

        const int di = (i >> 2) * ROWSTEP + (i & 3);
        float4* op4 = reinterpret_cast<float4*>(ob + (size_t)di * DOUT);
        op4[0] = make_float4(o[0], o[1], o[2],  o[3]);
        op4[1] = make_float4(o[4], o[5], o[6],  o[7]);
        op4[2] = make_float4(o[8], o[9], o[10], o[11]);
    }
}

extern "C" void kernel_launch(void* const* d_in, const int* in_sizes, int n_in,
                              void* d_out, int out_size, void* d_ws, size_t ws_size,
                              hipStream_t stream) {
    const float* x    = (const float*)d_in[0];   // (4096, 4096) f32
    const float* wgts = (const float*)d_in[1];   // (2048, 6)   f32
    // d_in[2] = connections — deterministic (3g+1+k) % DIN, not needed.
    float* out = (float*)d_out;                  // (4096, 6144) f32

    const int grid = 2 * NRB;                    // 512 blocks = 2 per CU
    fredkin_kernel<<<grid, 256, 0, stream>>>(x, wgts, out);
}